// Round 18
// baseline (157.470 us; speedup 1.0000x reference)
//
#include <hip/hip_runtime.h>

#define K_SPARSE 64
#define COLS     4096
#define NTHREADS 256
#define EPT      (COLS / NTHREADS)   // 16 elements per thread
#define VPT      (EPT / 4)           // 4 float4 chunks per thread
#define FAST_CAP 1024                // fast-path candidate cap
#define LIST_CAP (FAST_CAP + 8)      // + pad for b128 tail reads

typedef float nfloat4 __attribute__((ext_vector_type(4)));

// Order-preserving fp32 -> uint32 mapping (used ONLY by the exact fallback).
__device__ __forceinline__ unsigned mapf(unsigned b) {
    return (b & 0x80000000u) ? ~b : (b | 0x80000000u);
}

// Light barrier: execution sync + LDS visibility WITHOUT draining vmcnt,
// so outstanding nontemporal stores stay in flight across it (the
// __syncthreads vmcnt(0) drain is exactly what killed R15's prefetch).
// sched_barrier(0) pins ordering per guide rule #18.
__device__ __forceinline__ void lbar() {
    asm volatile("s_waitcnt lgkmcnt(0)" ::: "memory");
    __builtin_amdgcn_s_barrier();
    __builtin_amdgcn_sched_barrier(0);
}

__global__ __launch_bounds__(NTHREADS)
void ksparse_select(const float* __restrict__ x, float* __restrict__ out, int rows)
{
    const int row = blockIdx.x;
    if (row >= rows) return;
    const int t    = threadIdx.x;
    const int lane = t & 63;
    const int w    = t >> 6;          // wave id 0..3

    __shared__ __align__(16) float list[LIST_CAP];
    __shared__ unsigned wtot[4];
    __shared__ float s_kth;

    const float4* __restrict__ xrow =
        reinterpret_cast<const float4*>(x) + (size_t)row * (COLS / 4);
    nfloat4* __restrict__ orow =
        reinterpret_cast<nfloat4*>(out) + (size_t)row * (COLS / 4);

    // Row in registers as plain floats (f[16] -> ~24 VGPR total demand).
    float f[EPT];
#pragma unroll
    for (int i = 0; i < VPT; ++i) {
        float4 v = xrow[t + i * NTHREADS];
        f[i * 4 + 0] = v.x; f[i * 4 + 1] = v.y;
        f[i * 4 + 2] = v.z; f[i * 4 + 3] = v.w;
    }

    // --- Phase 1: threshold rungs (float domain). T=1.9 -> E[c]~118 on
    // N(0,1); T=0.9 -> E[c]~754. Speed-only; exactness from select/fallback.
    float fT = 0.0f; unsigned cnt = 0, base = 0, c = 0;
#pragma unroll
    for (int r = 0; r < 2; ++r) {
        fT = (r == 0) ? 1.9f : 0.9f;
        cnt = 0;
#pragma unroll
        for (int i = 0; i < EPT; ++i) cnt += (f[i] > fT) ? 1u : 0u;

        unsigned s = cnt;                    // wave inclusive prefix scan
#pragma unroll
        for (int off = 1; off < 64; off <<= 1) {
            unsigned v = __shfl_up(s, off, 64);
            if (lane >= off) s += v;
        }
        if (lane == 63) wtot[w] = s;
        lbar();                              // B1: wtot visible (LDS only)
        const unsigned c0 = wtot[0], c1 = wtot[1], c2 = wtot[2], c3 = wtot[3];
        c = c0 + c1 + c2 + c3;
        if (c >= K_SPARSE + 1 || r == 1) {
            base = (w > 0 ? c0 : 0u) + (w > 1 ? c1 : 0u) + (w > 2 ? c2 : 0u)
                 + s - cnt;                  // block-wide exclusive prefix
            break;
        }
        lbar();                              // B1b: wtot consumed before rewrite
    }

    if (c >= K_SPARSE + 1 && c <= FAST_CAP) {
        // kth > fT is now guaranteed (65 values exceed fT), so every chunk
        // with NO element > fT is all-zeros in the output: store it NOW.
        // These stores ride in flight across the light barriers below,
        // keeping the memory pipe busy during the select (~89% of write
        // traffic issued before kth is known).
        unsigned hm = 0;                     // bit i: chunk i has a candidate
#pragma unroll
        for (int i = 0; i < VPT; ++i) {
            const bool has = (f[i*4+0] > fT) | (f[i*4+1] > fT)
                           | (f[i*4+2] > fT) | (f[i*4+3] > fT);
            if (has) hm |= (1u << i);
            else {
                nfloat4 z = {0.0f, 0.0f, 0.0f, 0.0f};
                __builtin_nontemporal_store(z, &orow[t + i * NTHREADS]);
            }
        }

        // --- Phase 2: compact candidates (f > fT) to LDS. No atomics.
        unsigned pos = base;
#pragma unroll
        for (int i = 0; i < EPT; ++i) {
            if (f[i] > fT) list[pos++] = f[i];
        }
        if (t < 8) list[c + t] = -1.0e38f;   // pad: below every candidate
        lbar();                              // B2: list complete (LDS only)

        // --- Phase 3: exact tie-aware rank-K select among c candidates.
        const int nq = (int)((c + 3) >> 2);
        const nfloat4* listv = reinterpret_cast<const nfloat4*>(list);
        for (int j = t; j < (int)c; j += NTHREADS) {
            const float vj = list[j];
            unsigned g = 0, e = 0;
            for (int q = 0; q < nq; ++q) {
                const nfloat4 ql = listv[q]; // broadcast read: conflict-free
                g += (ql.x > vj) + (ql.y > vj) + (ql.z > vj) + (ql.w > vj);
                e += (ql.x == vj) + (ql.y == vj) + (ql.z == vj) + (ql.w == vj);
            }
            if (g <= (unsigned)K_SPARSE && (unsigned)K_SPARSE < g + e)
                s_kth = vj;                  // unique value; benign race
        }
        lbar();                              // B3: s_kth visible (LDS only)
        const float kth = s_kth;

        // --- Phase 4: store only the deferred candidate chunks, masked.
#pragma unroll
        for (int i = 0; i < VPT; ++i) {
            if (hm & (1u << i)) {
                nfloat4 o;
                o.x = (f[i*4+0] > kth) ? f[i*4+0] : 0.0f;
                o.y = (f[i*4+1] > kth) ? f[i*4+1] : 0.0f;
                o.z = (f[i*4+2] > kth) ? f[i*4+2] : 0.0f;
                o.w = (f[i*4+3] > kth) ? f[i*4+3] : 0.0f;
                __builtin_nontemporal_store(o, &orow[t + i * NTHREADS]);
            }
        }
    } else {
        // --- Fallback (exact for any input; ~never taken on N(0,1) data):
        // bitwise search in mapped-uint domain for kth = sorted[n-1-K].
        unsigned prefix = 0u;
        for (int b = 31; b >= 0; --b) {
            const unsigned trial = prefix | (1u << b);
            unsigned c2 = 0;
#pragma unroll
            for (int i = 0; i < EPT; ++i)
                c2 += (mapf(__float_as_uint(f[i])) >= trial) ? 1u : 0u;
#pragma unroll
            for (int off = 32; off >= 1; off >>= 1)
                c2 += __shfl_xor(c2, off, 64);       // wave butterfly reduce
            if (lane == 0) wtot[w] = c2;
            lbar();
            const unsigned tot = wtot[0] + wtot[1] + wtot[2] + wtot[3];
            if (tot >= K_SPARSE + 1) prefix = trial;
            lbar();                          // protect wtot before next bit
        }
        const unsigned kb = (prefix & 0x80000000u) ? (prefix ^ 0x80000000u) : ~prefix;
        const float kth = __uint_as_float(kb);

#pragma unroll
        for (int i = 0; i < VPT; ++i) {
            nfloat4 o;
            o.x = (f[i*4+0] > kth) ? f[i*4+0] : 0.0f;
            o.y = (f[i*4+1] > kth) ? f[i*4+1] : 0.0f;
            o.z = (f[i*4+2] > kth) ? f[i*4+2] : 0.0f;
            o.w = (f[i*4+3] > kth) ? f[i*4+3] : 0.0f;
            __builtin_nontemporal_store(o, &orow[t + i * NTHREADS]);
        }
    }
}

extern "C" void kernel_launch(void* const* d_in, const int* in_sizes, int n_in,
                              void* d_out, int out_size, void* d_ws, size_t ws_size,
                              hipStream_t stream) {
    const float* x = (const float*)d_in[0];
    float* out = (float*)d_out;
    const int rows = in_sizes[0] / COLS;
    ksparse_select<<<rows, NTHREADS, 0, stream>>>(x, out, rows);
}

// Round 19
// 71.889 us; speedup vs baseline: 2.1905x; 2.1905x over previous
//
#include <hip/hip_runtime.h>

#define K_SPARSE 64
#define COLS     4096
#define NTHREADS 256
#define EPT      (COLS / NTHREADS)   // 16 elements per thread
#define VPT      (EPT / 4)           // 4 float4 loads per thread
#define FAST_CAP 1024                // fast-path candidate cap
#define LIST_CAP (FAST_CAP + 8)      // + pad for b128 tail reads

typedef float    nfloat4 __attribute__((ext_vector_type(4)));
typedef unsigned nuint4  __attribute__((ext_vector_type(4)));

// Order-preserving fp32 -> uint32 mapping (ascending float order == ascending uint order)
__device__ __forceinline__ unsigned mapf(unsigned b) {
    return (b & 0x80000000u) ? ~b : (b | 0x80000000u);
}
__device__ __forceinline__ float unmapf(unsigned u) {
    unsigned b = (u & 0x80000000u) ? (u ^ 0x80000000u) : ~u;
    return __uint_as_float(b);
}

__global__ __launch_bounds__(NTHREADS)
void ksparse_select(const float* __restrict__ x, float* __restrict__ out, int rows)
{
    const int row = blockIdx.x;
    if (row >= rows) return;
    const int t    = threadIdx.x;
    const int lane = t & 63;
    const int w    = t >> 6;          // wave id 0..3

    __shared__ __align__(16) unsigned list[LIST_CAP];
    __shared__ unsigned wtot[4];
    __shared__ unsigned s_kth;

    const float4* __restrict__ xrow =
        reinterpret_cast<const float4*>(x) + (size_t)row * (COLS / 4);
    nfloat4* __restrict__ orow =
        reinterpret_cast<nfloat4*>(out) + (size_t)row * (COLS / 4);

    // Row lives in registers ONLY as mapped uints (u[16] ~ 16 VGPR demand;
    // floats reconstructed bit-exactly at store). Keeps us under the
    // allocator's pick -> no scratch spill (R7/R11/R12 lesson).
    unsigned u[EPT];
#pragma unroll
    for (int i = 0; i < VPT; ++i) {
        float4 v = xrow[t + i * NTHREADS];
        u[i * 4 + 0] = mapf(__float_as_uint(v.x));
        u[i * 4 + 1] = mapf(__float_as_uint(v.y));
        u[i * 4 + 2] = mapf(__float_as_uint(v.z));
        u[i * 4 + 3] = mapf(__float_as_uint(v.w));
    }

    // --- Phase 1: threshold rungs. mapf(1.9f)=0xBFF33333 (E[c]~118 on N(0,1)),
    // mapf(0.9f)=0xBF666666 (E[c]~754). Rungs affect speed only; exactness
    // comes from the select / the fallback.
    unsigned uT = 0, cnt = 0, base = 0, c = 0;
#pragma unroll
    for (int r = 0; r < 2; ++r) {
        uT = (r == 0) ? 0xBFF33333u : 0xBF666666u;
        cnt = 0;
#pragma unroll
        for (int i = 0; i < EPT; ++i) cnt += (u[i] > uT) ? 1u : 0u;

        unsigned s = cnt;                    // wave inclusive prefix scan
#pragma unroll
        for (int off = 1; off < 64; off <<= 1) {
            unsigned v = __shfl_up(s, off, 64);
            if (lane >= off) s += v;
        }
        if (lane == 63) wtot[w] = s;
        __syncthreads();                     // B1: wtot visible
        const unsigned c0 = wtot[0], c1 = wtot[1], c2 = wtot[2], c3 = wtot[3];
        c = c0 + c1 + c2 + c3;
        if (c >= K_SPARSE + 1 || r == 1) {
            base = (w > 0 ? c0 : 0u) + (w > 1 ? c1 : 0u) + (w > 2 ? c2 : 0u)
                 + s - cnt;                  // block-wide exclusive prefix
            break;
        }
        __syncthreads();                     // B1b: wtot consumed before rewrite
    }

    unsigned ukth;
    if (c >= K_SPARSE + 1 && c <= FAST_CAP) {
        // --- Phase 2: compact candidates (u > uT) to LDS. No atomics.
        unsigned pos = base;
#pragma unroll
        for (int i = 0; i < EPT; ++i) {
            if (u[i] > uT) list[pos++] = u[i];
        }
        if (t < 8) list[c + t] = 0u;         // pad so b128 tail reads are neutral
        __syncthreads();                     // B2: list complete

        // --- Phase 3: exact tie-aware rank-K select among c candidates.
        // v* unique with g(v*) <= K < g(v*)+e(v*), matching sorted[n-1-K].
        const int nq = (int)((c + 3) >> 2);
        const nuint4* listv = reinterpret_cast<const nuint4*>(list);
        for (int j = t; j < (int)c; j += NTHREADS) {
            const unsigned vj = list[j];
            unsigned g = 0, e = 0;
            for (int q = 0; q < nq; ++q) {
                const nuint4 ql = listv[q];  // broadcast read: all lanes same addr
                g += (ql.x > vj) + (ql.y > vj) + (ql.z > vj) + (ql.w > vj);
                e += (ql.x == vj) + (ql.y == vj) + (ql.z == vj) + (ql.w == vj);
            }
            if (g <= (unsigned)K_SPARSE && (unsigned)K_SPARSE < g + e)
                s_kth = vj;                  // unique value; benign same-value race
        }
        __syncthreads();                     // B3: s_kth visible
        ukth = s_kth;
    } else {
        // --- Fallback (exact for any input; ~never taken on N(0,1) data):
        // bitwise search for the largest v with |{u >= v}| >= K+1 == mapped kth.
        unsigned prefix = 0u;
        for (int b = 31; b >= 0; --b) {
            const unsigned trial = prefix | (1u << b);
            unsigned c2 = 0;
#pragma unroll
            for (int i = 0; i < EPT; ++i) c2 += (u[i] >= trial) ? 1u : 0u;
#pragma unroll
            for (int off = 32; off >= 1; off >>= 1)
                c2 += __shfl_xor(c2, off, 64);       // wave butterfly reduce
            if (lane == 0) wtot[w] = c2;
            __syncthreads();
            const unsigned tot = wtot[0] + wtot[1] + wtot[2] + wtot[3];
            if (tot >= K_SPARSE + 1) prefix = trial;
            __syncthreads();                 // protect wtot before next bit
        }
        ukth = prefix;                       // identical in every thread
    }

    // --- Phase 4: masked nt-store. Mapped-domain compare == float compare
    // (strictly monotone on non-NaN); value reconstructed bit-exactly.
#pragma unroll
    for (int i = 0; i < VPT; ++i) {
        nfloat4 o;
        o.x = (u[i * 4 + 0] > ukth) ? unmapf(u[i * 4 + 0]) : 0.0f;
        o.y = (u[i * 4 + 1] > ukth) ? unmapf(u[i * 4 + 1]) : 0.0f;
        o.z = (u[i * 4 + 2] > ukth) ? unmapf(u[i * 4 + 2]) : 0.0f;
        o.w = (u[i * 4 + 3] > ukth) ? unmapf(u[i * 4 + 3]) : 0.0f;
        __builtin_nontemporal_store(o, &orow[t + i * NTHREADS]);
    }
}

extern "C" void kernel_launch(void* const* d_in, const int* in_sizes, int n_in,
                              void* d_out, int out_size, void* d_ws, size_t ws_size,
                              hipStream_t stream) {
    const float* x = (const float*)d_in[0];
    float* out = (float*)d_out;
    const int rows = in_sizes[0] / COLS;
    ksparse_select<<<rows, NTHREADS, 0, stream>>>(x, out, rows);
}